// Round 1
// baseline (2213.000 us; speedup 1.0000x reference)
//
#include <hip/hip_runtime.h>

#define N_SAMPLES 32768
#define N_EMBED   10000
#define DIM       128
#define OUT_ELEMS 4194304     // 4*8*32*32*128
#define IDX_OFF   4194304
#define LOSS_OFF  4227072

// workspace byte offsets
#define WS_CNORM    0           // f32[10000]
#define WS_NEWSIZE  40000       // f32[10000]  (counts, then new_size in place)
#define WS_SUMS     80000       // f32[1280000] (sums, then new_mean in place)
#define WS_NSAMPLE  5200000     // f64[1]
#define WS_LOSS     5200008     // f64[1]
#define WS_PACKED   5200016     // u64[32768]

// ---------------- cluster norms ----------------
__global__ __launch_bounds__(64) void k_cnorm(const float* __restrict__ cm,
                                              float* __restrict__ cnorm) {
    int k = blockIdx.x;
    int lane = threadIdx.x;
    float2 e2 = ((const float2*)(cm + (size_t)k * DIM))[lane];
    float s = e2.x * e2.x + e2.y * e2.y;
    #pragma unroll
    for (int off = 32; off; off >>= 1) s += __shfl_down(s, off);
    if (lane == 0) cnorm[k] = s;
}

// ---------------- argmin over clusters ----------------
// grid = 512 blocks: sb = blockIdx & 127 (sample block), cs = blockIdx >> 7 (cluster split of 2500)
__global__ __launch_bounds__(256) void k_argmin(const float* __restrict__ inp,
                                                const float* __restrict__ cm,
                                                const float* __restrict__ cnorm,
                                                unsigned long long* __restrict__ packed) {
    __shared__ float se[32 * DIM];   // 16 KB tile: 32 clusters x 128 dims
    const int tid = threadIdx.x;
    const int sb = blockIdx.x & 127;
    const int cs = blockIdx.x >> 7;
    const int i = sb * 256 + tid;
    const int kbeg = cs * 2500, kend = kbeg + 2500;

    float4 xv[32];
    const float4* xp = (const float4*)(inp + (size_t)i * DIM);
    float a0 = 0.f, a1 = 0.f, a2 = 0.f, a3 = 0.f;
    #pragma unroll
    for (int t = 0; t < 32; ++t) {
        xv[t] = xp[t];
        a0 = fmaf(xv[t].x, xv[t].x, a0);
        a1 = fmaf(xv[t].y, xv[t].y, a1);
        a2 = fmaf(xv[t].z, xv[t].z, a2);
        a3 = fmaf(xv[t].w, xv[t].w, a3);
    }
    const float xnorm = (a0 + a2) + (a1 + a3);

    float bestd = 3.4e38f;
    int besti = kbeg;

    for (int k0 = kbeg; k0 < kend; k0 += 32) {
        int kt = kend - k0; if (kt > 32) kt = 32;
        __syncthreads();
        #pragma unroll
        for (int j = 0; j < 4; ++j) {
            int lin = tid + j * 256;        // 0..1023 float4 slots in tile
            int row = lin >> 5;             // 32 float4 per row
            int c4  = lin & 31;
            if (row < kt)
                ((float4*)se)[row * 32 + c4] =
                    ((const float4*)(cm + (size_t)(k0 + row) * DIM))[c4];
        }
        __syncthreads();
        for (int kk = 0; kk < kt; ++kk) {
            const float4* e4 = (const float4*)(se + kk * DIM);
            float d0 = 0.f, d1 = 0.f, d2 = 0.f, d3 = 0.f;
            #pragma unroll
            for (int t = 0; t < 32; ++t) {
                float4 e = e4[t];
                d0 = fmaf(e.x, xv[t].x, d0);
                d1 = fmaf(e.y, xv[t].y, d1);
                d2 = fmaf(e.z, xv[t].z, d2);
                d3 = fmaf(e.w, xv[t].w, d3);
            }
            float dot = (d0 + d2) + (d1 + d3);
            float dist = fmaf(-2.f, dot, xnorm) + cnorm[k0 + kk];
            if (dist < bestd) { bestd = dist; besti = k0 + kk; }
        }
    }

    unsigned int db = __float_as_uint(bestd);  // dist >= 0 -> bits monotonic
    unsigned long long pv = ((unsigned long long)db << 32) | (unsigned int)besti;
    atomicMin(&packed[i], pv);  // ties resolve to smallest index (low bits)
}

// ---------------- unpack argmin -> float idx ----------------
__global__ __launch_bounds__(256) void k_idx(const unsigned long long* __restrict__ packed,
                                             float* __restrict__ idxf) {
    int i = blockIdx.x * 256 + threadIdx.x;
    idxf[i] = (float)(unsigned int)(packed[i] & 0xFFFFFFFFull);
}

// ---------------- scatter: counts + sums ----------------
__global__ __launch_bounds__(256) void k_scatter(const float* __restrict__ inp,
                                                 const float* __restrict__ idxf,
                                                 float* __restrict__ sums,
                                                 float* __restrict__ counts) {
    int j = blockIdx.x * 256 + threadIdx.x;   // < 4194304
    int i = j >> 7, d = j & 127;
    int k = (int)idxf[i];
    atomicAdd(&sums[(size_t)k * DIM + d], inp[j]);
    if (d == 0) atomicAdd(&counts[k], 1.0f);
}

// ---------------- new_size + n_sample ----------------
__global__ __launch_bounds__(256) void k_newsize(const float* __restrict__ csize,
                                                 float* __restrict__ newsize,
                                                 double* __restrict__ nsample) {
    int k = blockIdx.x * 256 + threadIdx.x;
    float ns = 0.f;
    if (k < N_EMBED) {
        ns = csize[k] * 0.99f + newsize[k] * 0.01f;
        newsize[k] = ns;
    }
    float s = ns;
    #pragma unroll
    for (int off = 32; off; off >>= 1) s += __shfl_down(s, off);
    if ((threadIdx.x & 63) == 0) atomicAdd(nsample, (double)s);
}

// ---------------- new_mean (in place over sums) ----------------
__global__ __launch_bounds__(256) void k_newmean(const float* __restrict__ csum,
                                                 float* __restrict__ sums,
                                                 const float* __restrict__ newsize,
                                                 const double* __restrict__ nsample) {
    int j = blockIdx.x * 256 + threadIdx.x;   // < 1280000
    float nsmp = (float)(*nsample);
    int k = j >> 7;
    float sm = (newsize[k] + 1e-5f) * nsmp / (nsmp + 0.1f);
    sums[j] = (csum[j] * 0.99f + sums[j] * 0.01f) / sm;
}

// ---------------- gather + loss ----------------
__global__ __launch_bounds__(256) void k_gather(const float* __restrict__ inp,
                                                const float* __restrict__ nm,
                                                const float* __restrict__ idxf,
                                                float* __restrict__ out,
                                                double* __restrict__ lossacc) {
    int j = blockIdx.x * 256 + threadIdx.x;   // < 4194304
    int i = j >> 7, d = j & 127;
    int k = (int)idxf[i];
    float x = inp[j];
    float q = nm[(size_t)k * DIM + d];
    out[j] = x + (q - x);
    float dif = x - q;
    float e = dif * dif;
    #pragma unroll
    for (int off = 32; off; off >>= 1) e += __shfl_down(e, off);
    if ((threadIdx.x & 63) == 0) atomicAdd(lossacc, (double)e);
}

__global__ void k_lossfinal(const double* __restrict__ lossacc,
                            float* __restrict__ lossout) {
    *lossout = 0.25f * (float)(*lossacc / (double)OUT_ELEMS);
}

extern "C" void kernel_launch(void* const* d_in, const int* in_sizes, int n_in,
                              void* d_out, int out_size, void* d_ws, size_t ws_size,
                              hipStream_t stream) {
    const float* inp   = (const float*)d_in[0];
    const float* cmean = (const float*)d_in[1];
    const float* csize = (const float*)d_in[2];
    const float* csum  = (const float*)d_in[3];
    float* out = (float*)d_out;
    char*  ws  = (char*)d_ws;

    float*  cnorm   = (float*)(ws + WS_CNORM);
    float*  newsize = (float*)(ws + WS_NEWSIZE);
    float*  sums    = (float*)(ws + WS_SUMS);
    double* nsample = (double*)(ws + WS_NSAMPLE);
    double* lossacc = (double*)(ws + WS_LOSS);
    unsigned long long* packed = (unsigned long long*)(ws + WS_PACKED);

    // zero counts/sums/nsample/loss; fill packed with 0xFF (u64 max)
    hipMemsetAsync(ws + WS_NEWSIZE, 0, (WS_LOSS + 8) - WS_NEWSIZE, stream);
    hipMemsetAsync(ws + WS_PACKED, 0xFF, (size_t)N_SAMPLES * 8, stream);

    k_cnorm  <<<N_EMBED, 64, 0, stream>>>(cmean, cnorm);
    k_argmin <<<512, 256, 0, stream>>>(inp, cmean, cnorm, packed);
    k_idx    <<<N_SAMPLES / 256, 256, 0, stream>>>(packed, out + IDX_OFF);
    k_scatter<<<OUT_ELEMS / 256, 256, 0, stream>>>(inp, out + IDX_OFF, sums, newsize);
    k_newsize<<<(N_EMBED + 255) / 256, 256, 0, stream>>>(csize, newsize, nsample);
    k_newmean<<<(N_EMBED * DIM) / 256, 256, 0, stream>>>(csum, sums, newsize, nsample);
    k_gather <<<OUT_ELEMS / 256, 256, 0, stream>>>(inp, sums, out + IDX_OFF, out, lossacc);
    k_lossfinal<<<1, 1, 0, stream>>>(lossacc, out + LOSS_OFF);
}

// Round 2
// 888.245 us; speedup vs baseline: 2.4914x; 2.4914x over previous
//
#include <hip/hip_runtime.h>

#define N_SAMPLES 32768
#define N_EMBED   10000
#define KPAD      10240        // padded cluster count (40 * 256)
#define DIM       128
#define OUT_ELEMS 4194304      // 4*8*32*32*128
#define IDX_OFF   4194304
#define LOSS_OFF  4227072

#define NCB 40                 // cluster blocks (256 clusters each)
#define NSS 16                 // sample splits
#define SPB (N_SAMPLES / NSS)  // 2048 samples per block
#define STILES (SPB / 16)      // 128 sample tiles per block

// workspace byte offsets
#define WS_CNORM    0u          // f32[10240]
#define WS_NEWSIZE  65536u      // f32[10000] (counts then new_size)
#define WS_SUMS     131072u     // f32[1280000] (sums then new_mean)
#define WS_NSAMPLE  5251072u    // f64
#define WS_LOSS     5251080u    // f64
#define WS_PACKED   5251088u    // u64[32768]
#define WS_XHI      6291456u    // f16[32768*128]
#define WS_XLO      14680064u   // f16[32768*128]
#define WS_EHI      23068672u   // f16[10240*128]
#define WS_ELO      25690112u   // f16[10240*128]

typedef _Float16 f16;
typedef __attribute__((ext_vector_type(8))) _Float16 f16x8;
typedef __attribute__((ext_vector_type(4))) float f32x4;

__device__ inline unsigned long long shflx64(unsigned long long v, int m) {
    int lo = __shfl_xor((int)(unsigned int)(v & 0xffffffffull), m, 64);
    int hi = __shfl_xor((int)(unsigned int)(v >> 32), m, 64);
    return ((unsigned long long)(unsigned int)hi << 32) | (unsigned int)lo;
}

// ---------------- split X into f16 hi/lo ----------------
__global__ __launch_bounds__(256) void k_prepx(const float* __restrict__ x,
                                               f16* __restrict__ xhi,
                                               f16* __restrict__ xlo) {
    int j = blockIdx.x * 256 + threadIdx.x;        // chunk of 8, < 524288
    const float4* xp = (const float4*)(x + (size_t)j * 8);
    float4 a = xp[0], b = xp[1];
    float v[8] = {a.x, a.y, a.z, a.w, b.x, b.y, b.z, b.w};
    f16x8 hv, lv;
    #pragma unroll
    for (int i = 0; i < 8; ++i) {
        f16 h = (f16)v[i];
        hv[i] = h;
        lv[i] = (f16)(v[i] - (float)h);
    }
    *(f16x8*)(xhi + (size_t)j * 8) = hv;
    *(f16x8*)(xlo + (size_t)j * 8) = lv;
}

// ---------------- split E + cluster norms (padded to 10240) ----------------
__global__ __launch_bounds__(128) void k_prepe(const float* __restrict__ cm,
                                               f16* __restrict__ ehi,
                                               f16* __restrict__ elo,
                                               float* __restrict__ cnorm) {
    __shared__ float pw[2];
    int c = blockIdx.x, d = threadIdx.x;
    float e = (c < N_EMBED) ? cm[(size_t)c * DIM + d] : 0.f;
    f16 h = (f16)e;
    ehi[(size_t)c * DIM + d] = h;
    elo[(size_t)c * DIM + d] = (f16)(e - (float)h);
    float s = e * e;
    #pragma unroll
    for (int off = 32; off; off >>= 1) s += __shfl_down(s, off, 64);
    if ((threadIdx.x & 63) == 0) pw[threadIdx.x >> 6] = s;
    __syncthreads();
    if (threadIdx.x == 0) cnorm[c] = (c < N_EMBED) ? (pw[0] + pw[1]) : 3.0e38f;
}

// ---------------- MFMA argmin: score = cnorm - 2*dot ----------------
__global__ __launch_bounds__(256, 2) void k_argmin(const f16* __restrict__ xhi,
                                                   const f16* __restrict__ xlo,
                                                   const f16* __restrict__ ehi,
                                                   const f16* __restrict__ elo,
                                                   const float* __restrict__ cnorm,
                                                   unsigned long long* __restrict__ packed) {
    __shared__ unsigned long long lbest[4][16];
    const int tid = threadIdx.x;
    const int wave = tid >> 6;
    const int lane = tid & 63;
    const int l15 = lane & 15, q = (lane >> 4) & 3;
    const int cbi = blockIdx.x % NCB, ssi = blockIdx.x / NCB;
    const int wcb = cbi * 256 + wave * 64;   // this wave's 64 clusters
    const int sbase = ssi * SPB;

    // E fragments resident in registers: e[tile t][kstep], B-frag lane map:
    // col = l15 (cluster), k = ks*32 + q*8 + e  -> contiguous 8 f16 in E row
    f16x8 eh[4][4], el[4][4];
    float cn[4];
    #pragma unroll
    for (int t = 0; t < 4; ++t) {
        const int c = wcb + t * 16 + l15;
        const size_t rb = (size_t)c * DIM + q * 8;
        #pragma unroll
        for (int ks = 0; ks < 4; ++ks) {
            eh[t][ks] = *(const f16x8*)(ehi + rb + ks * 32);
            el[t][ks] = *(const f16x8*)(elo + rb + ks * 32);
        }
        cn[t] = cnorm[c];
    }

    for (int st = 0; st < STILES; ++st) {
        const int s0 = sbase + st * 16;
        const size_t xb = (size_t)(s0 + l15) * DIM + q * 8;
        f16x8 ah[4], al[4];
        #pragma unroll
        for (int ks = 0; ks < 4; ++ks) {
            ah[ks] = *(const f16x8*)(xhi + xb + ks * 32);
            al[ks] = *(const f16x8*)(xlo + xb + ks * 32);
        }
        f32x4 acc[4] = {{0,0,0,0},{0,0,0,0},{0,0,0,0},{0,0,0,0}};
        #pragma unroll
        for (int ks = 0; ks < 4; ++ks) {
            #pragma unroll
            for (int t = 0; t < 4; ++t) {
                acc[t] = __builtin_amdgcn_mfma_f32_16x16x32_f16(ah[ks], eh[t][ks], acc[t], 0, 0, 0);
                acc[t] = __builtin_amdgcn_mfma_f32_16x16x32_f16(ah[ks], el[t][ks], acc[t], 0, 0, 0);
                acc[t] = __builtin_amdgcn_mfma_f32_16x16x32_f16(al[ks], eh[t][ks], acc[t], 0, 0, 0);
                acc[t] = __builtin_amdgcn_mfma_f32_16x16x32_f16(al[ks], el[t][ks], acc[t], 0, 0, 0);
            }
        }
        // D[row = q*4+r][col = l15] = dot(sample s0+q*4+r, cluster wcb+t*16+l15)
        unsigned long long pk[4];
        #pragma unroll
        for (int r = 0; r < 4; ++r) {
            unsigned long long best = ~0ull;
            #pragma unroll
            for (int t = 0; t < 4; ++t) {
                float s = fmaf(-2.f, acc[t][r], cn[t]);
                unsigned int b = __float_as_uint(s);
                b = (b & 0x80000000u) ? ~b : (b | 0x80000000u);   // sortable key
                unsigned long long p =
                    ((unsigned long long)b << 32) | (unsigned int)(wcb + t * 16 + l15);
                best = best < p ? best : p;
            }
            pk[r] = best;
        }
        #pragma unroll
        for (int m = 1; m < 16; m <<= 1) {
            #pragma unroll
            for (int r = 0; r < 4; ++r) {
                unsigned long long o = shflx64(pk[r], m);
                pk[r] = pk[r] < o ? pk[r] : o;
            }
        }
        // lanes with (l15 < 4) hold rows q*4 + l15; static-select to avoid scratch
        unsigned long long v = (l15 & 2) ? ((l15 & 1) ? pk[3] : pk[2])
                                         : ((l15 & 1) ? pk[1] : pk[0]);
        if (l15 < 4) lbest[wave][q * 4 + l15] = v;
        __syncthreads();
        if (tid < 16) {
            unsigned long long m0 = lbest[0][tid] < lbest[1][tid] ? lbest[0][tid] : lbest[1][tid];
            unsigned long long m1 = lbest[2][tid] < lbest[3][tid] ? lbest[2][tid] : lbest[3][tid];
            unsigned long long mm = m0 < m1 ? m0 : m1;
            atomicMin(&packed[s0 + tid], mm);
        }
        __syncthreads();
    }
}

// ---------------- unpack argmin -> float idx ----------------
__global__ __launch_bounds__(256) void k_idx(const unsigned long long* __restrict__ packed,
                                             float* __restrict__ idxf) {
    int i = blockIdx.x * 256 + threadIdx.x;
    idxf[i] = (float)(unsigned int)(packed[i] & 0xFFFFFFFFull);
}

// ---------------- scatter: counts + sums ----------------
__global__ __launch_bounds__(256) void k_scatter(const float* __restrict__ inp,
                                                 const unsigned long long* __restrict__ packed,
                                                 float* __restrict__ sums,
                                                 float* __restrict__ counts) {
    int j = blockIdx.x * 256 + threadIdx.x;   // < 4194304
    int i = j >> 7, d = j & 127;
    int k = (int)(unsigned int)(packed[i] & 0xFFFFFFFFull);
    atomicAdd(&sums[(size_t)k * DIM + d], inp[j]);
    if (d == 0) atomicAdd(&counts[k], 1.0f);
}

// ---------------- new_size + n_sample ----------------
__global__ __launch_bounds__(256) void k_newsize(const float* __restrict__ csize,
                                                 float* __restrict__ newsize,
                                                 double* __restrict__ nsample) {
    int k = blockIdx.x * 256 + threadIdx.x;
    float ns = 0.f;
    if (k < N_EMBED) {
        ns = csize[k] * 0.99f + newsize[k] * 0.01f;
        newsize[k] = ns;
    }
    float s = ns;
    #pragma unroll
    for (int off = 32; off; off >>= 1) s += __shfl_down(s, off, 64);
    if ((threadIdx.x & 63) == 0) atomicAdd(nsample, (double)s);
}

// ---------------- new_mean (in place over sums) ----------------
__global__ __launch_bounds__(256) void k_newmean(const float* __restrict__ csum,
                                                 float* __restrict__ sums,
                                                 const float* __restrict__ newsize,
                                                 const double* __restrict__ nsample) {
    int j = blockIdx.x * 256 + threadIdx.x;   // < 1280000
    float nsmp = (float)(*nsample);
    int k = j >> 7;
    float sm = (newsize[k] + 1e-5f) * nsmp / (nsmp + 0.1f);
    sums[j] = (csum[j] * 0.99f + sums[j] * 0.01f) / sm;
}

// ---------------- gather + output + two-stage loss ----------------
__global__ __launch_bounds__(256) void k_gather(const float* __restrict__ inp,
                                                const float* __restrict__ nm,
                                                const unsigned long long* __restrict__ packed,
                                                float* __restrict__ out,
                                                double* __restrict__ lossacc) {
    __shared__ double pw[4];
    int t0 = blockIdx.x * 256 + threadIdx.x;    // grid 512 -> t0 < 131072
    double de = 0.0;
    #pragma unroll
    for (int it = 0; it < 8; ++it) {
        int j4 = t0 + it * 131072;              // float4 index < 1048576
        int i = j4 >> 5, d4 = j4 & 31;
        int k = (int)(unsigned int)(packed[i] & 0xFFFFFFFFull);
        float4 x = ((const float4*)inp)[j4];
        float4 qv = ((const float4*)(nm + (size_t)k * DIM))[d4];
        float4 o;
        o.x = x.x + (qv.x - x.x); o.y = x.y + (qv.y - x.y);
        o.z = x.z + (qv.z - x.z); o.w = x.w + (qv.w - x.w);
        ((float4*)out)[j4] = o;
        float dx = x.x - qv.x, dy = x.y - qv.y, dz = x.z - qv.z, dw = x.w - qv.w;
        de += (double)(dx * dx + dy * dy + dz * dz + dw * dw);
    }
    #pragma unroll
    for (int off = 32; off; off >>= 1) de += __shfl_down(de, off, 64);
    if ((threadIdx.x & 63) == 0) pw[threadIdx.x >> 6] = de;
    __syncthreads();
    if (threadIdx.x == 0)
        atomicAdd(lossacc, pw[0] + pw[1] + pw[2] + pw[3]);
}

__global__ void k_lossfinal(const double* __restrict__ lossacc,
                            float* __restrict__ lossout) {
    *lossout = 0.25f * (float)(*lossacc / (double)OUT_ELEMS);
}

extern "C" void kernel_launch(void* const* d_in, const int* in_sizes, int n_in,
                              void* d_out, int out_size, void* d_ws, size_t ws_size,
                              hipStream_t stream) {
    const float* inp   = (const float*)d_in[0];
    const float* cmean = (const float*)d_in[1];
    const float* csize = (const float*)d_in[2];
    const float* csum  = (const float*)d_in[3];
    float* out = (float*)d_out;
    char*  ws  = (char*)d_ws;

    float*  cnorm   = (float*)(ws + WS_CNORM);
    float*  newsize = (float*)(ws + WS_NEWSIZE);
    float*  sums    = (float*)(ws + WS_SUMS);
    double* nsample = (double*)(ws + WS_NSAMPLE);
    double* lossacc = (double*)(ws + WS_LOSS);
    unsigned long long* packed = (unsigned long long*)(ws + WS_PACKED);
    f16* xhi = (f16*)(ws + WS_XHI);
    f16* xlo = (f16*)(ws + WS_XLO);
    f16* ehi = (f16*)(ws + WS_EHI);
    f16* elo = (f16*)(ws + WS_ELO);

    // zero counts/sums/nsample/loss; fill packed with 0xFF (u64 max)
    hipMemsetAsync(ws + WS_NEWSIZE, 0, (WS_LOSS + 8) - WS_NEWSIZE, stream);
    hipMemsetAsync(ws + WS_PACKED, 0xFF, (size_t)N_SAMPLES * 8, stream);

    k_prepx  <<<2048, 256, 0, stream>>>(inp, xhi, xlo);
    k_prepe  <<<KPAD, 128, 0, stream>>>(cmean, ehi, elo, cnorm);
    k_argmin <<<NCB * NSS, 256, 0, stream>>>(xhi, xlo, ehi, elo, cnorm, packed);
    k_idx    <<<N_SAMPLES / 256, 256, 0, stream>>>(packed, out + IDX_OFF);
    k_scatter<<<OUT_ELEMS / 256, 256, 0, stream>>>(inp, packed, sums, newsize);
    k_newsize<<<(N_EMBED + 255) / 256, 256, 0, stream>>>(csize, newsize, nsample);
    k_newmean<<<(N_EMBED * DIM) / 256, 256, 0, stream>>>(csum, sums, newsize, nsample);
    k_gather <<<512, 256, 0, stream>>>(inp, sums, packed, out, lossacc);
    k_lossfinal<<<1, 1, 0, stream>>>(lossacc, out + LOSS_OFF);
}

// Round 3
// 433.167 us; speedup vs baseline: 5.1089x; 2.0506x over previous
//
#include <hip/hip_runtime.h>

#define N_SAMPLES 32768
#define N_EMBED   10000
#define KPAD      10240        // padded cluster count
#define DIM       128
#define OUT_ELEMS 4194304      // 4*8*32*32*128
#define IDX_OFF   4194304
#define LOSS_OFF  4227072

// workspace byte offsets
#define WS_CNORM    0u          // f32[10240]
#define WS_NEWSIZE  65536u      // f32[10000] (counts then new_size)
#define WS_SUMS     131072u     // f32[1280000] (sums then new_mean)
#define WS_NSAMPLE  5251072u    // f64
#define WS_LOSS     5251080u    // f64
#define WS_XHI      6291456u    // f16[32768*128]
#define WS_XLO      14680064u   // f16[32768*128]
#define WS_EHI      23068672u   // f16[10240*128]
#define WS_ELO      25690112u   // f16[10240*128]

typedef _Float16 f16;
typedef __attribute__((ext_vector_type(8))) _Float16 f16x8;
typedef __attribute__((ext_vector_type(4))) float f32x4;

__device__ inline unsigned long long shflx64(unsigned long long v, int m) {
    int lo = __shfl_xor((int)(unsigned int)(v & 0xffffffffull), m, 64);
    int hi = __shfl_xor((int)(unsigned int)(v >> 32), m, 64);
    return ((unsigned long long)(unsigned int)hi << 32) | (unsigned int)lo;
}

// ---------------- split X into f16 hi/lo ----------------
__global__ __launch_bounds__(256) void k_prepx(const float* __restrict__ x,
                                               f16* __restrict__ xhi,
                                               f16* __restrict__ xlo) {
    int j = blockIdx.x * 256 + threadIdx.x;        // chunk of 8, < 524288
    const float4* xp = (const float4*)(x + (size_t)j * 8);
    float4 a = xp[0], b = xp[1];
    float v[8] = {a.x, a.y, a.z, a.w, b.x, b.y, b.z, b.w};
    f16x8 hv, lv;
    #pragma unroll
    for (int i = 0; i < 8; ++i) {
        f16 h = (f16)v[i];
        hv[i] = h;
        lv[i] = (f16)(v[i] - (float)h);
    }
    *(f16x8*)(xhi + (size_t)j * 8) = hv;
    *(f16x8*)(xlo + (size_t)j * 8) = lv;
}

// ---------------- split E + cluster norms (padded to 10240) ----------------
__global__ __launch_bounds__(128) void k_prepe(const float* __restrict__ cm,
                                               f16* __restrict__ ehi,
                                               f16* __restrict__ elo,
                                               float* __restrict__ cnorm) {
    __shared__ float pw[2];
    int c = blockIdx.x, d = threadIdx.x;
    float e = (c < N_EMBED) ? cm[(size_t)c * DIM + d] : 0.f;
    f16 h = (f16)e;
    ehi[(size_t)c * DIM + d] = h;
    elo[(size_t)c * DIM + d] = (f16)(e - (float)h);
    float s = e * e;
    #pragma unroll
    for (int off = 32; off; off >>= 1) s += __shfl_down(s, off, 64);
    if ((threadIdx.x & 63) == 0) pw[threadIdx.x >> 6] = s;
    __syncthreads();
    if (threadIdx.x == 0) cnorm[c] = (c < N_EMBED) ? (pw[0] + pw[1]) : 3.0e38f;
}

// ---------------- MFMA argmin: sample-stationary, clusters stream ----------------
// Block: 64 samples (4 x 16-sample B-frag tiles in regs, same for all 4 waves).
// Wave w streams clusters [w*2560, (w+1)*2560): A-frag rows, prefetch ping-pong.
// D[row = q*4+r][col = l15]: row -> cluster-in-tile, col -> sample. Per-lane
// running argmin in registers; single cross-q + cross-wave reduce at the end.
__global__ __launch_bounds__(256, 2) void k_argmin(const f16* __restrict__ xhi,
                                                   const f16* __restrict__ xlo,
                                                   const f16* __restrict__ ehi,
                                                   const f16* __restrict__ elo,
                                                   const float* __restrict__ cnorm,
                                                   float* __restrict__ idxf) {
    __shared__ unsigned long long lb[4][64];
    const int tid = threadIdx.x;
    const int wave = tid >> 6, lane = tid & 63;
    const int l15 = lane & 15, q = lane >> 4;
    const int sbase = blockIdx.x * 64;

    // sample B-frags: col = l15 -> sample sbase+st*16+l15, k = ks*32 + q*8 + e
    f16x8 bh[4][4], bl[4][4];
    #pragma unroll
    for (int st = 0; st < 4; ++st) {
        const size_t xb = (size_t)(sbase + st * 16 + l15) * DIM + q * 8;
        #pragma unroll
        for (int ks = 0; ks < 4; ++ks) {
            bh[st][ks] = *(const f16x8*)(xhi + xb + ks * 32);
            bl[st][ks] = *(const f16x8*)(xlo + xb + ks * 32);
        }
    }

    float best[4] = {3.4e38f, 3.4e38f, 3.4e38f, 3.4e38f};
    int besti[4] = {0, 0, 0, 0};
    const int cbeg = wave * (KPAD / 4), cend = cbeg + (KPAD / 4);

    // prefetch first cluster tile
    f16x8 ahf[4], alf[4];
    float cnr[4];
    {
        const size_t ab = (size_t)(cbeg + l15) * DIM + q * 8;
        #pragma unroll
        for (int ks = 0; ks < 4; ++ks) {
            ahf[ks] = *(const f16x8*)(ehi + ab + ks * 32);
            alf[ks] = *(const f16x8*)(elo + ab + ks * 32);
        }
        float4 c4 = *(const float4*)(cnorm + cbeg + q * 4);
        cnr[0] = c4.x; cnr[1] = c4.y; cnr[2] = c4.z; cnr[3] = c4.w;
    }

    for (int c0 = cbeg; c0 < cend; c0 += 16) {
        // issue next tile's loads before the MFMA cluster
        const int cn0 = (c0 + 16 < cend) ? (c0 + 16) : cbeg;
        const size_t ab = (size_t)(cn0 + l15) * DIM + q * 8;
        f16x8 nah[4], nal[4];
        #pragma unroll
        for (int ks = 0; ks < 4; ++ks) {
            nah[ks] = *(const f16x8*)(ehi + ab + ks * 32);
            nal[ks] = *(const f16x8*)(elo + ab + ks * 32);
        }
        float4 nc4 = *(const float4*)(cnorm + cn0 + q * 4);

        f32x4 acc[4] = {{0,0,0,0},{0,0,0,0},{0,0,0,0},{0,0,0,0}};
        #pragma unroll
        for (int ks = 0; ks < 4; ++ks) {
            #pragma unroll
            for (int st = 0; st < 4; ++st) {
                acc[st] = __builtin_amdgcn_mfma_f32_16x16x32_f16(ahf[ks], bh[st][ks], acc[st], 0, 0, 0);
                acc[st] = __builtin_amdgcn_mfma_f32_16x16x32_f16(ahf[ks], bl[st][ks], acc[st], 0, 0, 0);
                acc[st] = __builtin_amdgcn_mfma_f32_16x16x32_f16(alf[ks], bh[st][ks], acc[st], 0, 0, 0);
                acc[st] = __builtin_amdgcn_mfma_f32_16x16x32_f16(alf[ks], bl[st][ks], acc[st], 0, 0, 0);
            }
        }

        // score = cnorm[c] - 2*dot; per-lane running argmin (ascending c, strict <)
        const int ib = c0 + q * 4;
        #pragma unroll
        for (int st = 0; st < 4; ++st) {
            #pragma unroll
            for (int r = 0; r < 4; ++r) {
                float s = fmaf(-2.f, acc[st][r], cnr[r]);
                if (s < best[st]) { best[st] = s; besti[st] = ib + r; }
            }
        }

        // rotate prefetch
        #pragma unroll
        for (int ks = 0; ks < 4; ++ks) { ahf[ks] = nah[ks]; alf[ks] = nal[ks]; }
        cnr[0] = nc4.x; cnr[1] = nc4.y; cnr[2] = nc4.z; cnr[3] = nc4.w;
    }

    // reduce over q (lanes l15+16q) then across waves via LDS
    #pragma unroll
    for (int st = 0; st < 4; ++st) {
        unsigned int b = __float_as_uint(best[st]);
        b = (b & 0x80000000u) ? ~b : (b | 0x80000000u);   // sortable key
        unsigned long long p = ((unsigned long long)b << 32) | (unsigned int)besti[st];
        unsigned long long o = shflx64(p, 16); p = p < o ? p : o;
        o = shflx64(p, 32); p = p < o ? p : o;
        if (q == 0) lb[wave][st * 16 + l15] = p;
    }
    __syncthreads();
    if (tid < 64) {
        unsigned long long m0 = lb[0][tid] < lb[1][tid] ? lb[0][tid] : lb[1][tid];
        unsigned long long m1 = lb[2][tid] < lb[3][tid] ? lb[2][tid] : lb[3][tid];
        unsigned long long mm = m0 < m1 ? m0 : m1;
        idxf[sbase + tid] = (float)(unsigned int)(mm & 0xFFFFFFFFull);
    }
}

// ---------------- scatter: counts + sums ----------------
__global__ __launch_bounds__(256) void k_scatter(const float* __restrict__ inp,
                                                 const float* __restrict__ idxf,
                                                 float* __restrict__ sums,
                                                 float* __restrict__ counts) {
    int j = blockIdx.x * 256 + threadIdx.x;   // < 4194304
    int i = j >> 7, d = j & 127;
    int k = (int)idxf[i];
    atomicAdd(&sums[(size_t)k * DIM + d], inp[j]);
    if (d == 0) atomicAdd(&counts[k], 1.0f);
}

// ---------------- new_size + n_sample ----------------
__global__ __launch_bounds__(256) void k_newsize(const float* __restrict__ csize,
                                                 float* __restrict__ newsize,
                                                 double* __restrict__ nsample) {
    int k = blockIdx.x * 256 + threadIdx.x;
    float ns = 0.f;
    if (k < N_EMBED) {
        ns = csize[k] * 0.99f + newsize[k] * 0.01f;
        newsize[k] = ns;
    }
    float s = ns;
    #pragma unroll
    for (int off = 32; off; off >>= 1) s += __shfl_down(s, off, 64);
    if ((threadIdx.x & 63) == 0) atomicAdd(nsample, (double)s);
}

// ---------------- new_mean (in place over sums) ----------------
__global__ __launch_bounds__(256) void k_newmean(const float* __restrict__ csum,
                                                 float* __restrict__ sums,
                                                 const float* __restrict__ newsize,
                                                 const double* __restrict__ nsample) {
    int j = blockIdx.x * 256 + threadIdx.x;   // < 1280000
    float nsmp = (float)(*nsample);
    int k = j >> 7;
    float sm = (newsize[k] + 1e-5f) * nsmp / (nsmp + 0.1f);
    sums[j] = (csum[j] * 0.99f + sums[j] * 0.01f) / sm;
}

// ---------------- gather + output + two-stage loss ----------------
__global__ __launch_bounds__(256) void k_gather(const float* __restrict__ inp,
                                                const float* __restrict__ nm,
                                                const float* __restrict__ idxf,
                                                float* __restrict__ out,
                                                double* __restrict__ lossacc) {
    __shared__ double pw[4];
    int t0 = blockIdx.x * 256 + threadIdx.x;    // grid 512 -> t0 < 131072
    double de = 0.0;
    #pragma unroll
    for (int it = 0; it < 8; ++it) {
        int j4 = t0 + it * 131072;              // float4 index < 1048576
        int i = j4 >> 5, d4 = j4 & 31;
        int k = (int)idxf[i];
        float4 x = ((const float4*)inp)[j4];
        float4 qv = ((const float4*)(nm + (size_t)k * DIM))[d4];
        float4 o;
        o.x = x.x + (qv.x - x.x); o.y = x.y + (qv.y - x.y);
        o.z = x.z + (qv.z - x.z); o.w = x.w + (qv.w - x.w);
        ((float4*)out)[j4] = o;
        float dx = x.x - qv.x, dy = x.y - qv.y, dz = x.z - qv.z, dw = x.w - qv.w;
        de += (double)(dx * dx + dy * dy + dz * dz + dw * dw);
    }
    #pragma unroll
    for (int off = 32; off; off >>= 1) de += __shfl_down(de, off, 64);
    if ((threadIdx.x & 63) == 0) pw[threadIdx.x >> 6] = de;
    __syncthreads();
    if (threadIdx.x == 0)
        atomicAdd(lossacc, pw[0] + pw[1] + pw[2] + pw[3]);
}

__global__ void k_lossfinal(const double* __restrict__ lossacc,
                            float* __restrict__ lossout) {
    *lossout = 0.25f * (float)(*lossacc / (double)OUT_ELEMS);
}

extern "C" void kernel_launch(void* const* d_in, const int* in_sizes, int n_in,
                              void* d_out, int out_size, void* d_ws, size_t ws_size,
                              hipStream_t stream) {
    const float* inp   = (const float*)d_in[0];
    const float* cmean = (const float*)d_in[1];
    const float* csize = (const float*)d_in[2];
    const float* csum  = (const float*)d_in[3];
    float* out = (float*)d_out;
    char*  ws  = (char*)d_ws;

    float*  cnorm   = (float*)(ws + WS_CNORM);
    float*  newsize = (float*)(ws + WS_NEWSIZE);
    float*  sums    = (float*)(ws + WS_SUMS);
    double* nsample = (double*)(ws + WS_NSAMPLE);
    double* lossacc = (double*)(ws + WS_LOSS);
    f16* xhi = (f16*)(ws + WS_XHI);
    f16* xlo = (f16*)(ws + WS_XLO);
    f16* ehi = (f16*)(ws + WS_EHI);
    f16* elo = (f16*)(ws + WS_ELO);
    float* idxf = out + IDX_OFF;

    // zero counts/sums/nsample/loss
    hipMemsetAsync(ws + WS_NEWSIZE, 0, (WS_LOSS + 8) - WS_NEWSIZE, stream);

    k_prepx  <<<2048, 256, 0, stream>>>(inp, xhi, xlo);
    k_prepe  <<<KPAD, 128, 0, stream>>>(cmean, ehi, elo, cnorm);
    k_argmin <<<N_SAMPLES / 64, 256, 0, stream>>>(xhi, xlo, ehi, elo, cnorm, idxf);
    k_scatter<<<OUT_ELEMS / 256, 256, 0, stream>>>(inp, idxf, sums, newsize);
    k_newsize<<<(N_EMBED + 255) / 256, 256, 0, stream>>>(csize, newsize, nsample);
    k_newmean<<<(N_EMBED * DIM) / 256, 256, 0, stream>>>(csum, sums, newsize, nsample);
    k_gather <<<512, 256, 0, stream>>>(inp, sums, idxf, out, lossacc);
    k_lossfinal<<<1, 1, 0, stream>>>(lossacc, out + LOSS_OFF);
}

// Round 4
// 319.166 us; speedup vs baseline: 6.9337x; 1.3572x over previous
//
#include <hip/hip_runtime.h>

#define N_SAMPLES 32768
#define N_EMBED   10000
#define KPAD      10240        // padded cluster count
#define QLEN      2560         // clusters per quarter
#define DIM       128
#define OUT_ELEMS 4194304      // 4*8*32*32*128
#define IDX_OFF   4194304
#define LOSS_OFF  4227072

// workspace byte offsets
#define WS_CNH      0u          // f32[10240]  = -||e||^2/2  (padded: -1.5e38)
#define WS_NEWSIZE  65536u      // f32[10000] (counts then new_size)
#define WS_SUMS     131072u     // f32[1280000] (sums then new_mean)
#define WS_NSAMPLE  5251072u    // f64
#define WS_LOSS     5251080u    // f64
#define WS_PACKED   5251088u    // u64[32768]
#define WS_XHI      6291456u    // f16[32768*128]
#define WS_XLO      14680064u   // f16[32768*128]
#define WS_EHI      23068672u   // f16[10240*128]
#define WS_ELO      25690112u   // f16[10240*128]

typedef _Float16 f16;
typedef __attribute__((ext_vector_type(8))) _Float16 f16x8;
typedef __attribute__((ext_vector_type(4))) float f32x4;

__device__ inline unsigned long long shflx64(unsigned long long v, int m) {
    int lo = __shfl_xor((int)(unsigned int)(v & 0xffffffffull), m, 64);
    int hi = __shfl_xor((int)(unsigned int)(v >> 32), m, 64);
    return ((unsigned long long)(unsigned int)hi << 32) | (unsigned int)lo;
}

// ---------------- split X into f16 hi/lo ----------------
__global__ __launch_bounds__(256) void k_prepx(const float* __restrict__ x,
                                               f16* __restrict__ xhi,
                                               f16* __restrict__ xlo) {
    int j = blockIdx.x * 256 + threadIdx.x;        // chunk of 8, < 524288
    const float4* xp = (const float4*)(x + (size_t)j * 8);
    float4 a = xp[0], b = xp[1];
    float v[8] = {a.x, a.y, a.z, a.w, b.x, b.y, b.z, b.w};
    f16x8 hv, lv;
    #pragma unroll
    for (int i = 0; i < 8; ++i) {
        f16 h = (f16)v[i];
        hv[i] = h;
        lv[i] = (f16)(v[i] - (float)h);
    }
    *(f16x8*)(xhi + (size_t)j * 8) = hv;
    *(f16x8*)(xlo + (size_t)j * 8) = lv;
}

// ---------------- split E + negated-half norms (padded to 10240) ----------------
__global__ __launch_bounds__(128) void k_prepe(const float* __restrict__ cm,
                                               f16* __restrict__ ehi,
                                               f16* __restrict__ elo,
                                               float* __restrict__ cnh) {
    __shared__ float pw[2];
    int c = blockIdx.x, d = threadIdx.x;
    float e = (c < N_EMBED) ? cm[(size_t)c * DIM + d] : 0.f;
    f16 h = (f16)e;
    ehi[(size_t)c * DIM + d] = h;
    elo[(size_t)c * DIM + d] = (f16)(e - (float)h);
    float s = e * e;
    #pragma unroll
    for (int off = 32; off; off >>= 1) s += __shfl_down(s, off, 64);
    if ((threadIdx.x & 63) == 0) pw[threadIdx.x >> 6] = s;
    __syncthreads();
    if (threadIdx.x == 0)
        cnh[c] = (c < N_EMBED) ? -0.5f * (pw[0] + pw[1]) : -1.5e38f;
}

// ---------------- MFMA argmin ----------------
// 512 blocks = 128 sample-groups x 4 cluster-quarters. Block: 4 waves x 64
// samples each; 32-cluster tiles staged in LDS (XOR-swizzled, double-buffered)
// and shared by all 4 waves. acc init = -||e||^2/2 -> per-lane argMAX of acc.
// 3-pass f16 split (hh, h*lo_x, lo_e*h); xlo*elo term ~3e-7, dropped.
__global__ __launch_bounds__(256, 2) void k_argmin(const f16* __restrict__ xhi,
                                                   const f16* __restrict__ xlo,
                                                   const f16* __restrict__ ehi,
                                                   const f16* __restrict__ elo,
                                                   const float* __restrict__ cnh,
                                                   unsigned long long* __restrict__ packed) {
    __shared__ __align__(16) char lds[32768];   // 2 bufs x (32 rows x 256B hi + 8KB lo)
    const int tid = threadIdx.x;
    const int wave = tid >> 6, lane = tid & 63;
    const int l15 = lane & 15, q = lane >> 4;
    // block mapping: XCD (blockIdx%8 heuristic) pinned to one cluster quarter
    const int g = ((blockIdx.x >> 3) << 1) | (blockIdx.x & 1);   // sample group 0..127
    const int kq = (blockIdx.x >> 1) & 3;                        // cluster quarter
    const int kbase = kq * QLEN;
    const int sbase = g * 256 + wave * 64;

    // resident sample B-frags: col=l15 -> sample sbase+st*16+l15, k = ks*32+q*8+e
    f16x8 bh[4][4], bl[4][4];
    #pragma unroll
    for (int st = 0; st < 4; ++st) {
        const size_t xb = (size_t)(sbase + st * 16 + l15) * DIM + q * 8;
        #pragma unroll
        for (int ks = 0; ks < 4; ++ks) {
            bh[st][ks] = *(const f16x8*)(xhi + xb + ks * 32);
            bl[st][ks] = *(const f16x8*)(xlo + xb + ks * 32);
        }
    }

    // LDS read addrs (lane-invariant across iters): row=l15 (+ct*4096 imm),
    // chunk = (ks*4+q) ^ (l15&7)  ->  ra[ks] = base ^ (ks<<6)
    int ra[4];
    {
        int rb = l15 * 256 + ((q ^ (l15 & 3)) << 4) + (((l15 >> 2) & 1) << 6);
        #pragma unroll
        for (int ks = 0; ks < 4; ++ks) ra[ks] = rb ^ (ks << 6);
    }
    // LDS write addrs: linear chunk idx -> row=idx>>4, ch=idx&15, swz ch^(row&7)
    const int r0 = tid >> 4, c0w = tid & 15;
    const int wr0 = r0 * 256 + ((c0w ^ (r0 & 7)) << 4);
    const int r1 = (tid + 256) >> 4, c1w = tid & 15;
    const int wr1 = r1 * 256 + ((c1w ^ (r1 & 7)) << 4);

    float best[4] = {-3.4e38f, -3.4e38f, -3.4e38f, -3.4e38f};
    int bi[4] = {0, 0, 0, 0};

    // prologue: stage tile 0 into buf 0, load its cnh
    float4 cnA, cnB;
    {
        const f16* gh = ehi + (size_t)kbase * DIM;
        const f16* gl = elo + (size_t)kbase * DIM;
        f16x8 sh0 = *(const f16x8*)(gh + tid * 8);
        f16x8 sh1 = *(const f16x8*)(gh + tid * 8 + 2048);
        f16x8 sl0 = *(const f16x8*)(gl + tid * 8);
        f16x8 sl1 = *(const f16x8*)(gl + tid * 8 + 2048);
        cnA = *(const float4*)(cnh + kbase + q * 4);
        cnB = *(const float4*)(cnh + kbase + 16 + q * 4);
        *(f16x8*)(lds + wr0) = sh0;
        *(f16x8*)(lds + wr1) = sh1;
        *(f16x8*)(lds + 8192 + wr0) = sl0;
        *(f16x8*)(lds + 8192 + wr1) = sl1;
        __syncthreads();
    }

    int cur = 0;
    for (int it = 0; it < 80; ++it) {
        const int c0 = kbase + it * 32;
        // issue next tile's global loads early (latency hides under MFMA)
        f16x8 sh0, sh1, sl0, sl1; float4 cnAn, cnBn;
        if (it < 79) {
            const f16* gh = ehi + (size_t)(c0 + 32) * DIM;
            const f16* gl = elo + (size_t)(c0 + 32) * DIM;
            sh0 = *(const f16x8*)(gh + tid * 8);
            sh1 = *(const f16x8*)(gh + tid * 8 + 2048);
            sl0 = *(const f16x8*)(gl + tid * 8);
            sl1 = *(const f16x8*)(gl + tid * 8 + 2048);
            cnAn = *(const float4*)(cnh + c0 + 32 + q * 4);
            cnBn = *(const float4*)(cnh + c0 + 48 + q * 4);
        }

        const char* ldsr = lds + cur * 16384;
        #pragma unroll
        for (int ct = 0; ct < 2; ++ct) {
            f16x8 ah[4], al[4];
            #pragma unroll
            for (int ks = 0; ks < 4; ++ks) {
                ah[ks] = *(const f16x8*)(ldsr + ra[ks] + ct * 4096);
                al[ks] = *(const f16x8*)(ldsr + ra[ks] + ct * 4096 + 8192);
            }
            const float4 cn = ct ? cnB : cnA;
            f32x4 ini = {cn.x, cn.y, cn.z, cn.w};
            f32x4 acc[4] = {ini, ini, ini, ini};
            #pragma unroll
            for (int ks = 0; ks < 4; ++ks) {
                #pragma unroll
                for (int st = 0; st < 4; ++st)
                    acc[st] = __builtin_amdgcn_mfma_f32_16x16x32_f16(ah[ks], bh[st][ks], acc[st], 0, 0, 0);
                #pragma unroll
                for (int st = 0; st < 4; ++st)
                    acc[st] = __builtin_amdgcn_mfma_f32_16x16x32_f16(ah[ks], bl[st][ks], acc[st], 0, 0, 0);
                #pragma unroll
                for (int st = 0; st < 4; ++st)
                    acc[st] = __builtin_amdgcn_mfma_f32_16x16x32_f16(al[ks], bh[st][ks], acc[st], 0, 0, 0);
            }
            // argMAX of acc; candidate index stored without lane-q offset
            #pragma unroll
            for (int r = 0; r < 4; ++r) {
                const int cand = c0 + ct * 16 + r;   // wave-uniform
                #pragma unroll
                for (int st = 0; st < 4; ++st) {
                    bool gt = acc[st][r] > best[st];
                    best[st] = gt ? acc[st][r] : best[st];
                    bi[st] = gt ? cand : bi[st];
                }
            }
        }

        if (it < 79) {
            char* ldsw = lds + (cur ^ 1) * 16384;
            *(f16x8*)(ldsw + wr0) = sh0;
            *(f16x8*)(ldsw + wr1) = sh1;
            *(f16x8*)(ldsw + 8192 + wr0) = sl0;
            *(f16x8*)(ldsw + 8192 + wr1) = sl1;
            __syncthreads();
            cnA = cnAn; cnB = cnBn;
            cur ^= 1;
        }
    }

    // per-wave reduce over q groups, then one atomicMin per sample
    const int q4 = q * 4;
    #pragma unroll
    for (int st = 0; st < 4; ++st) {
        float sc = -2.0f * best[st];
        unsigned int b = __float_as_uint(sc);
        b = (b & 0x80000000u) ? ~b : (b | 0x80000000u);   // sortable key
        unsigned long long p = ((unsigned long long)b << 32) | (unsigned int)(bi[st] + q4);
        unsigned long long o = shflx64(p, 16); p = p < o ? p : o;
        o = shflx64(p, 32); p = p < o ? p : o;
        if (q == 0) atomicMin(&packed[sbase + st * 16 + l15], p);
    }
}

// ---------------- unpack argmin -> float idx ----------------
__global__ __launch_bounds__(256) void k_idx(const unsigned long long* __restrict__ packed,
                                             float* __restrict__ idxf) {
    int i = blockIdx.x * 256 + threadIdx.x;
    idxf[i] = (float)(unsigned int)(packed[i] & 0xFFFFFFFFull);
}

// ---------------- scatter: counts + sums ----------------
__global__ __launch_bounds__(256) void k_scatter(const float* __restrict__ inp,
                                                 const unsigned long long* __restrict__ packed,
                                                 float* __restrict__ sums,
                                                 float* __restrict__ counts) {
    int j = blockIdx.x * 256 + threadIdx.x;   // < 4194304
    int i = j >> 7, d = j & 127;
    int k = (int)(unsigned int)(packed[i] & 0xFFFFFFFFull);
    atomicAdd(&sums[(size_t)k * DIM + d], inp[j]);
    if (d == 0) atomicAdd(&counts[k], 1.0f);
}

// ---------------- new_size + n_sample ----------------
__global__ __launch_bounds__(256) void k_newsize(const float* __restrict__ csize,
                                                 float* __restrict__ newsize,
                                                 double* __restrict__ nsample) {
    int k = blockIdx.x * 256 + threadIdx.x;
    float ns = 0.f;
    if (k < N_EMBED) {
        ns = csize[k] * 0.99f + newsize[k] * 0.01f;
        newsize[k] = ns;
    }
    float s = ns;
    #pragma unroll
    for (int off = 32; off; off >>= 1) s += __shfl_down(s, off, 64);
    if ((threadIdx.x & 63) == 0) atomicAdd(nsample, (double)s);
}

// ---------------- new_mean (in place over sums) ----------------
__global__ __launch_bounds__(256) void k_newmean(const float* __restrict__ csum,
                                                 float* __restrict__ sums,
                                                 const float* __restrict__ newsize,
                                                 const double* __restrict__ nsample) {
    int j = blockIdx.x * 256 + threadIdx.x;   // < 1280000
    float nsmp = (float)(*nsample);
    int k = j >> 7;
    float sm = (newsize[k] + 1e-5f) * nsmp / (nsmp + 0.1f);
    sums[j] = (csum[j] * 0.99f + sums[j] * 0.01f) / sm;
}

// ---------------- gather + output + two-stage loss ----------------
__global__ __launch_bounds__(256) void k_gather(const float* __restrict__ inp,
                                                const float* __restrict__ nm,
                                                const unsigned long long* __restrict__ packed,
                                                float* __restrict__ out,
                                                double* __restrict__ lossacc) {
    __shared__ double pw[4];
    int t0 = blockIdx.x * 256 + threadIdx.x;    // grid 512 -> t0 < 131072
    double de = 0.0;
    #pragma unroll
    for (int it = 0; it < 8; ++it) {
        int j4 = t0 + it * 131072;              // float4 index < 1048576
        int i = j4 >> 5, d4 = j4 & 31;
        int k = (int)(unsigned int)(packed[i] & 0xFFFFFFFFull);
        float4 x = ((const float4*)inp)[j4];
        float4 qv = ((const float4*)(nm + (size_t)k * DIM))[d4];
        float4 o;
        o.x = x.x + (qv.x - x.x); o.y = x.y + (qv.y - x.y);
        o.z = x.z + (qv.z - x.z); o.w = x.w + (qv.w - x.w);
        ((float4*)out)[j4] = o;
        float dx = x.x - qv.x, dy = x.y - qv.y, dz = x.z - qv.z, dw = x.w - qv.w;
        de += (double)(dx * dx + dy * dy + dz * dz + dw * dw);
    }
    #pragma unroll
    for (int off = 32; off; off >>= 1) de += __shfl_down(de, off, 64);
    if ((threadIdx.x & 63) == 0) pw[threadIdx.x >> 6] = de;
    __syncthreads();
    if (threadIdx.x == 0)
        atomicAdd(lossacc, pw[0] + pw[1] + pw[2] + pw[3]);
}

__global__ void k_lossfinal(const double* __restrict__ lossacc,
                            float* __restrict__ lossout) {
    *lossout = 0.25f * (float)(*lossacc / (double)OUT_ELEMS);
}

extern "C" void kernel_launch(void* const* d_in, const int* in_sizes, int n_in,
                              void* d_out, int out_size, void* d_ws, size_t ws_size,
                              hipStream_t stream) {
    const float* inp   = (const float*)d_in[0];
    const float* cmean = (const float*)d_in[1];
    const float* csize = (const float*)d_in[2];
    const float* csum  = (const float*)d_in[3];
    float* out = (float*)d_out;
    char*  ws  = (char*)d_ws;

    float*  cnh     = (float*)(ws + WS_CNH);
    float*  newsize = (float*)(ws + WS_NEWSIZE);
    float*  sums    = (float*)(ws + WS_SUMS);
    double* nsample = (double*)(ws + WS_NSAMPLE);
    double* lossacc = (double*)(ws + WS_LOSS);
    unsigned long long* packed = (unsigned long long*)(ws + WS_PACKED);
    f16* xhi = (f16*)(ws + WS_XHI);
    f16* xlo = (f16*)(ws + WS_XLO);
    f16* ehi = (f16*)(ws + WS_EHI);
    f16* elo = (f16*)(ws + WS_ELO);

    // zero counts/sums/nsample/loss; fill packed with 0xFF (u64 max)
    hipMemsetAsync(ws + WS_NEWSIZE, 0, (WS_LOSS + 8) - WS_NEWSIZE, stream);
    hipMemsetAsync(ws + WS_PACKED, 0xFF, (size_t)N_SAMPLES * 8, stream);

    k_prepx  <<<2048, 256, 0, stream>>>(inp, xhi, xlo);
    k_prepe  <<<KPAD, 128, 0, stream>>>(cmean, ehi, elo, cnh);
    k_argmin <<<512, 256, 0, stream>>>(xhi, xlo, ehi, elo, cnh, packed);
    k_idx    <<<N_SAMPLES / 256, 256, 0, stream>>>(packed, out + IDX_OFF);
    k_scatter<<<OUT_ELEMS / 256, 256, 0, stream>>>(inp, packed, sums, newsize);
    k_newsize<<<(N_EMBED + 255) / 256, 256, 0, stream>>>(csize, newsize, nsample);
    k_newmean<<<(N_EMBED * DIM) / 256, 256, 0, stream>>>(csum, sums, newsize, nsample);
    k_gather <<<512, 256, 0, stream>>>(inp, sums, packed, out, lossacc);
    k_lossfinal<<<1, 1, 0, stream>>>(lossacc, out + LOSS_OFF);
}